// Round 1
// baseline (36.483 us; speedup 1.0000x reference)
//
#include <hip/hip_runtime.h>
#include <math.h>

// Shapes (NCHW, f32):
//  x1: (8,128,128,128)  -> maxpool2 -> (8,128,64,64), tiled x2  in C
//  x2: (8, 32,256,256)  -> maxpool4 -> (8, 32,64,64), tiled x8  in C
//  x3: (8,  2,512,512)  -> maxpool8 -> (8,  2,64,64), tiled x128 in C
//  ff : (8,256,64,64)
//  out = relu(y1 + y2 + y3 + ff), (8,256,64,64)
//
// One block per (b, output row h): 8*64 = 512 blocks, 256 threads.
// y2/y3 pooled rows staged in LDS; y1 pooled in registers and reused for
// output channels c1 and c1+128 (so x1 is read exactly once).

__global__ __launch_bounds__(256) void fused_ff_block3(
    const float* __restrict__ x1, const float* __restrict__ x2,
    const float* __restrict__ x3, const float* __restrict__ ff,
    float* __restrict__ out)
{
    __shared__ float y2s[32][64];   // 8 KiB
    __shared__ float y3s[2][64];    // 512 B

    const int bid = blockIdx.x;
    const int b   = bid >> 6;       // 0..7
    const int h   = bid & 63;       // output row 0..63
    const int tid = threadIdx.x;

    // ---- Phase 1: y3 row (2 ch x 64 w), each = max over 8x8 window of x3 ----
    if (tid < 128) {
        const int c3 = tid >> 6;    // 0..1
        const int w  = tid & 63;
        const float* p = x3 + (size_t)b * 524288 + (size_t)c3 * 262144
                            + (size_t)(h * 8) * 512 + (size_t)w * 8;
        float m = -INFINITY;
        #pragma unroll
        for (int r = 0; r < 8; ++r) {
            const float4 a = *reinterpret_cast<const float4*>(p + (size_t)r * 512);
            const float4 c = *reinterpret_cast<const float4*>(p + (size_t)r * 512 + 4);
            m = fmaxf(m, fmaxf(fmaxf(fmaxf(a.x, a.y), fmaxf(a.z, a.w)),
                               fmaxf(fmaxf(c.x, c.y), fmaxf(c.z, c.w))));
        }
        y3s[c3][w] = m;
    }

    // ---- Phase 2: y2 row (32 ch x 64 w), each = max over 4x4 window of x2 ----
    #pragma unroll
    for (int v = tid; v < 2048; v += 256) {
        const int c2 = v >> 6;      // 0..31
        const int w  = v & 63;
        const float* p = x2 + (size_t)b * 2097152 + (size_t)c2 * 65536
                            + (size_t)(h * 4) * 256 + (size_t)w * 4;
        float m = -INFINITY;
        #pragma unroll
        for (int r = 0; r < 4; ++r) {
            const float4 a = *reinterpret_cast<const float4*>(p + (size_t)r * 256);
            m = fmaxf(m, fmaxf(fmaxf(a.x, a.y), fmaxf(a.z, a.w)));
        }
        y2s[c2][w] = m;
    }

    __syncthreads();

    // ---- Phase 3: 2x2 pool of x1 in regs; combine + relu; write c1 and c1+128 ----
    const int w     = tid & 63;
    const int clane = tid >> 6;     // 0..3
    #pragma unroll 4
    for (int it = 0; it < 32; ++it) {
        const int c1 = it * 4 + clane;    // 0..127
        const float* p = x1 + (size_t)b * 2097152 + (size_t)c1 * 16384
                            + (size_t)(h * 2) * 128 + (size_t)w * 2;
        const float2 a  = *reinterpret_cast<const float2*>(p);
        const float2 bb = *reinterpret_cast<const float2*>(p + 128);
        const float p1 = fmaxf(fmaxf(a.x, a.y), fmaxf(bb.x, bb.y));
        const float s  = p1 + y2s[c1 & 31][w] + y3s[c1 & 1][w];

        const size_t obase = (size_t)b * 1048576 + (size_t)h * 64 + (size_t)w;
        const size_t o0 = obase + (size_t)c1 * 4096;
        const size_t o1 = obase + (size_t)(c1 + 128) * 4096;
        out[o0] = fmaxf(s + ff[o0], 0.0f);
        out[o1] = fmaxf(s + ff[o1], 0.0f);
    }
}

extern "C" void kernel_launch(void* const* d_in, const int* in_sizes, int n_in,
                              void* d_out, int out_size, void* d_ws, size_t ws_size,
                              hipStream_t stream) {
    const float* x1 = (const float*)d_in[0];
    const float* x2 = (const float*)d_in[1];
    const float* x3 = (const float*)d_in[2];
    const float* ff = (const float*)d_in[3];
    float* out = (float*)d_out;

    dim3 grid(512);   // 8 batches * 64 output rows
    dim3 block(256);
    fused_ff_block3<<<grid, block, 0, stream>>>(x1, x2, x3, ff, out);
}